// Round 6
// baseline (583.367 us; speedup 1.0000x reference)
//
#include <hip/hip_runtime.h>
#include <stdint.h>

typedef __attribute__((ext_vector_type(4))) float f32x4;
typedef __attribute__((ext_vector_type(8))) __bf16 bf16x8;
typedef __attribute__((ext_vector_type(4))) unsigned int u32x4;
typedef __attribute__((ext_vector_type(4))) unsigned short u16x4;

#define TOK 49
#define NHEAD 16
#define HDIM 32
#define CDIM 512
#define NB 2048
#define MTOT (NB * TOK) /* 100352 */
#define ATT_SCALE 0.17677669529663687f

__device__ __forceinline__ unsigned short f2bf(float f) {
  uint32_t u = __builtin_bit_cast(uint32_t, f);
  u += 0x7FFFu + ((u >> 16) & 1u);
  return (unsigned short)(u >> 16);
}

__device__ __forceinline__ void gl_lds16(const void* g, const void* lds) {
  __builtin_amdgcn_global_load_lds(
      (__attribute__((address_space(1))) void*)(uintptr_t)g,
      (__attribute__((address_space(3))) void*)(uint32_t)(uintptr_t)lds,
      16, 0, 0);
}

__device__ __forceinline__ f32x4 mfma16(bf16x8 a, bf16x8 b, f32x4 c) {
  return __builtin_amdgcn_mfma_f32_16x16x32_bf16(a, b, c, 0, 0, 0);
}

// ---- K0a: W_eff = W_qkv + B_up @ A_down, to bf16 [1536][512] ----
__global__ __launch_bounds__(256) void k_prep_weff(
    const float* __restrict__ Wqkv, const float* __restrict__ Bup,
    const float* __restrict__ Adown, unsigned short* __restrict__ weff) {
  int idx = blockIdx.x * 256 + threadIdx.x;
  if (idx >= 3 * CDIM * CDIM) return;
  int o = idx >> 9, i = idx & 511;
  float v = Wqkv[idx];
#pragma unroll
  for (int r = 0; r < 4; r++) v += Bup[o * 4 + r] * Adown[r * 512 + i];
  weff[idx] = f2bf(v);
}

// ---- K0b: fp32 -> bf16 vectorized convert (weights only now) ----
__global__ __launch_bounds__(256) void k_conv4(
    const float* __restrict__ src, unsigned short* __restrict__ dst, int n4) {
  for (int i = blockIdx.x * blockDim.x + threadIdx.x; i < n4;
       i += gridDim.x * blockDim.x) {
    f32x4 v = *(const f32x4*)(src + (size_t)i * 4);
    u16x4 o;
    o[0] = f2bf(v[0]); o[1] = f2bf(v[1]); o[2] = f2bf(v[2]); o[3] = f2bf(v[3]);
    *(u16x4*)(dst + (size_t)i * 4) = o;
  }
}

// ---- 256x256 tile, BK=64, 8-wave GEMM + LDS-staged coalesced epilogue ----
// C = A @ Bw^T + bias. Bw [N][512] bf16 (B^T form).
// AF32: A is fp32 [M][512]; reg-staged (global f32x4 -> cvt -> ds_write) with
// the same 16B-slot XOR swizzle; fuses the x->bf16 convert into the GEMM.
// !AF32: A is bf16, staged via global_load_lds (pre-swizzled source).
template <int NT, bool SPLIT, bool AF32>
__global__ __launch_bounds__(512, 1) void k_gemm256(
    const void* __restrict__ Ain, const unsigned short* __restrict__ Bw,
    const float* __restrict__ bias,
    unsigned short* __restrict__ qo, unsigned short* __restrict__ ko,
    unsigned short* __restrict__ vo, float* __restrict__ fo) {
  // 128KB: [A buf0 | A buf1 | B buf0 | B buf1], 16384 ushorts each.
  __shared__ __attribute__((aligned(16))) unsigned short smem[65536];
  const unsigned short* Ab = (const unsigned short*)Ain;
  const float* Af = (const float*)Ain;
  const int t = threadIdx.x;
  const int l = t & 63;
  const int l15 = l & 15, lq = l >> 4;
  const int w = t >> 6;
  const int wr = w >> 2, wc = w & 3;  // 2 x 4 wave grid, wave owns 128x64
  const int bid = blockIdx.x;
  const int lb = (bid & 7) * ((int)gridDim.x >> 3) + (bid >> 3);
  const int mt = lb / NT, nt = lb % NT;
  const size_t m0 = (size_t)mt * 256;
  const int n0 = nt * 256;

  auto stageA = [&](int kt, int bb) {  // !AF32 path
    unsigned short* dst = smem + bb * 16384;
#pragma unroll
    for (int q = 0; q < 4; ++q) {
      const int li = q * 512 + t;  // 16B-chunk index in 256x64 tile
      const int row = li >> 3, sl = li & 7;
      gl_lds16(Ab + (m0 + row) * CDIM + kt * 64 + ((sl ^ (row & 7)) << 3),
               &dst[li * 8]);
    }
  };
  auto stageB = [&](int kt, int bb) {
    unsigned short* dst = smem + 32768 + bb * 16384;
#pragma unroll
    for (int q = 0; q < 4; ++q) {
      const int li = q * 512 + t;
      const int row = li >> 3, sl = li & 7;
      gl_lds16(Bw + (size_t)(n0 + row) * CDIM + kt * 64 + ((sl ^ (row & 7)) << 3),
               &dst[li * 8]);
    }
  };

  // AF32 reg-staging: half h covers chunks q = 2h, 2h+1 (4 f32x4 = 16 VGPR)
  f32x4 ar[4];
  auto issueAh = [&](int kt, int h) {
#pragma unroll
    for (int q = 0; q < 2; ++q) {
      const int li = (h * 2 + q) * 512 + t;
      const int row = li >> 3, sl = li & 7;
      const float* p =
          Af + (m0 + row) * CDIM + kt * 64 + ((sl ^ (row & 7)) << 3);
      ar[q * 2] = *(const f32x4*)p;
      ar[q * 2 + 1] = *(const f32x4*)(p + 4);
    }
  };
  auto writeAh = [&](int bb, int h) {
    unsigned short* dst = smem + bb * 16384;
#pragma unroll
    for (int q = 0; q < 2; ++q) {
      const int li = (h * 2 + q) * 512 + t;
      u32x4 wv;
      wv[0] = (uint32_t)f2bf(ar[q * 2][0]) | ((uint32_t)f2bf(ar[q * 2][1]) << 16);
      wv[1] = (uint32_t)f2bf(ar[q * 2][2]) | ((uint32_t)f2bf(ar[q * 2][3]) << 16);
      wv[2] = (uint32_t)f2bf(ar[q * 2 + 1][0]) |
              ((uint32_t)f2bf(ar[q * 2 + 1][1]) << 16);
      wv[3] = (uint32_t)f2bf(ar[q * 2 + 1][2]) |
              ((uint32_t)f2bf(ar[q * 2 + 1][3]) << 16);
      *(u32x4*)&dst[li * 8] = wv;
    }
  };

  f32x4 acc[8][4] = {};
  // prologue: tile 0
  if constexpr (AF32) {
    issueAh(0, 0);
    stageB(0, 0);
    writeAh(0, 0);  // compiler-inserted vmcnt wait on ar
    issueAh(0, 1);
    writeAh(0, 1);
    asm volatile("s_waitcnt lgkmcnt(0)" ::: "memory");
  } else {
    stageA(0, 0);
    stageB(0, 0);
  }

  for (int kt = 0; kt < 8; ++kt) {
    const int cur = kt & 1, nb = cur ^ 1;
    if (kt < 7) {
      if constexpr (AF32) issueAh(kt + 1, 0);
      else stageA(kt + 1, nb);
      stageB(kt + 1, nb);
      // tile kt's B (and A for !AF32) landed; tile kt+1's 8 stay in flight
      asm volatile("s_waitcnt vmcnt(8)" ::: "memory");
    } else {
      asm volatile("s_waitcnt vmcnt(0)" ::: "memory");
    }
    __builtin_amdgcn_s_barrier();
    asm volatile("" ::: "memory");  // keep ds_reads below the barrier
    const unsigned short* bufA = smem + cur * 16384;
    const unsigned short* bufB = smem + 32768 + cur * 16384;

    // B fragments: loaded ONCE per K-tile, live across all 4 phases
    bf16x8 bfr[4][2];
#pragma unroll
    for (int c = 0; c < 4; ++c) {
      const int r = wc * 64 + c * 16 + l15;
#pragma unroll
      for (int h = 0; h < 2; ++h)
        bfr[c][h] = __builtin_bit_cast(
            bf16x8,
            *(const u32x4*)&bufB[r * 64 + (((lq + h * 4) ^ (r & 7)) << 3)]);
    }

#pragma unroll
    for (int p = 0; p < 4; ++p) {
      bf16x8 af[2][2];
#pragma unroll
      for (int rr = 0; rr < 2; ++rr) {
        const int r = wr * 128 + (p * 2 + rr) * 16 + l15;
#pragma unroll
        for (int h = 0; h < 2; ++h)
          af[rr][h] = __builtin_bit_cast(
              bf16x8,
              *(const u32x4*)&bufA[r * 64 + (((lq + h * 4) ^ (r & 7)) << 3)]);
      }
      __builtin_amdgcn_s_setprio(1);
#pragma unroll
      for (int rr = 0; rr < 2; ++rr) {
#pragma unroll
        for (int c = 0; c < 4; ++c) {
          acc[p * 2 + rr][c] = mfma16(af[rr][0], bfr[c][0], acc[p * 2 + rr][c]);
          acc[p * 2 + rr][c] = mfma16(af[rr][1], bfr[c][1], acc[p * 2 + rr][c]);
        }
      }
      __builtin_amdgcn_s_setprio(0);
      if constexpr (AF32) {
        if (p == 1 && kt < 7) {
          writeAh(nb, 0);       // A(kt+1) half0 -> LDS (auto vmcnt wait)
          issueAh(kt + 1, 1);   // half1 loads overlap phases 2-3
        }
        if (p == 3 && kt < 7) writeAh(nb, 1);
      }
    }
    if constexpr (AF32)
      asm volatile("s_waitcnt lgkmcnt(0)" ::: "memory");  // drain ds_writes
    asm volatile("" ::: "memory");
    __builtin_amdgcn_s_barrier();  // all reads of buf[cur] done
  }

  // ---- LDS-staged coalesced epilogue (slot^row swizzled) ----
  __syncthreads();  // drain all LDS traffic before repurposing smem
  if constexpr (SPLIT) {
    unsigned short* ep = smem + w * 8192;  // 128 rows x 64 cols bf16 (16KB)
#pragma unroll
    for (int J = 0; J < 4; ++J) {
      const int colb = n0 + wc * 64 + J * 16 + l15;
      const float bv = bias[colb];
      const int sl0 = J * 2 + (l15 >> 3);
#pragma unroll
      for (int I = 0; I < 8; ++I) {
#pragma unroll
        for (int r = 0; r < 4; ++r) {
          const int row = I * 16 + lq * 4 + r;
          ep[row * 64 + ((sl0 ^ (row & 7)) << 3) + (l15 & 7)] =
              f2bf(acc[I][J][r] + bv);
        }
      }
    }
    __syncthreads();
    // read back 256 sub-rows (128 m x 2 heads) of 64B; 4 lanes per sub-row
#pragma unroll
    for (int rnd = 0; rnd < 16; ++rnd) {
      const int sub = rnd * 16 + (l >> 2);
      const int mloc = sub >> 1, hd2 = sub & 1;
      const int colh = n0 + wc * 64 + hd2 * 32;
      const int which = colh >> 9;
      const int hh = (colh >> 5) & 15;
      unsigned short* dst = which == 0 ? qo : (which == 1 ? ko : vo);
      const uint32_t mg = (uint32_t)(m0 + wr * 128 + mloc);
      const uint32_t bw_ = mg / 49u;
      const uint32_t nn = mg - bw_ * 49u;
      const int sl = hd2 * 4 + (l & 3);
      u32x4 v = *(const u32x4*)&ep[mloc * 64 + ((sl ^ (mloc & 7)) << 3)];
      *(u32x4*)&dst[((size_t)(bw_ * 16u + hh) * 49u + nn) * 32u + (l & 3) * 8] =
          v;
    }
  } else {
    float* ep32 = (float*)smem + w * 4096;  // 64 rows x 64 cols f32 (16KB)
#pragma unroll
    for (int ch = 0; ch < 2; ++ch) {
#pragma unroll
      for (int J = 0; J < 4; ++J) {
        const int colb = n0 + wc * 64 + J * 16 + l15;
        const float bv = bias[colb];
        const int sl0 = J * 4 + (l15 >> 2);
#pragma unroll
        for (int Ii = 0; Ii < 4; ++Ii) {
#pragma unroll
          for (int r = 0; r < 4; ++r) {
            const int row = Ii * 16 + lq * 4 + r;
            ep32[row * 64 + ((sl0 ^ (row & 7)) << 2) + (l15 & 3)] =
                acc[ch * 4 + Ii][J][r] + bv;
          }
        }
      }
      __syncthreads();
#pragma unroll
      for (int rnd = 0; rnd < 16; ++rnd) {
        const int row = rnd * 4 + (l >> 4);
        const int sl = l & 15;
        f32x4 v = *(const f32x4*)&ep32[row * 64 + ((sl ^ (row & 7)) << 2)];
        const size_t mg = m0 + wr * 128 + ch * 64 + row;
        *(f32x4*)&fo[mg * CDIM + n0 + wc * 64 + (l & 15) * 4] = v;
      }
      __syncthreads();
    }
  }
}

// ---- K2: window attention, one wave per (b,h) ---- (unchanged this round)
__global__ __launch_bounds__(256) void k_attn(
    const unsigned short* __restrict__ qb, const unsigned short* __restrict__ kb,
    const unsigned short* __restrict__ vb, const float* __restrict__ mask,
    unsigned short* __restrict__ ao) {
  __shared__ __attribute__((aligned(16))) unsigned short sP[4][64 * 64];
  __shared__ __attribute__((aligned(16))) unsigned short sV[4][32 * 64];
  const int t = threadIdx.x;
  const int l = t & 63, w = t >> 6;
  const int l15 = l & 15, lq = l >> 4;
  const int pair = blockIdx.x * 4 + w;
  const int b = pair >> 4, h = pair & 15;
  const size_t base = (size_t)pair * (TOK * HDIM);
  unsigned short* P = sP[w];
  unsigned short* Vt = sV[w];

  bf16x8 qf[4], kf[4];
#pragma unroll
  for (int i = 0; i < 4; i++)
    qf[i] = __builtin_bit_cast(
        bf16x8, *(const u32x4*)(qb + base + (size_t)(i * 16 + l15) * 32 + lq * 8));
#pragma unroll
  for (int i = 0; i < 4; i++)
    kf[i] = __builtin_bit_cast(
        bf16x8, *(const u32x4*)(kb + base + (size_t)(i * 16 + l15) * 32 + lq * 8));
  u32x4 vr[4];
#pragma unroll
  for (int j = 0; j < 4; j++)
    vr[j] = *(const u32x4*)(vb + base + (size_t)l * 32 + j * 8);

  // S = Q K^T (64x64 padded; valid 49x49)
  f32x4 s[4][4];
  __builtin_amdgcn_s_setprio(1);
#pragma unroll
  for (int i = 0; i < 4; i++) {
#pragma unroll
    for (int j = 0; j < 4; j++) s[i][j] = mfma16(qf[i], kf[j], (f32x4)0.0f);
  }
  __builtin_amdgcn_s_setprio(0);

  // V^T -> LDS [d=32][token=64] swizzled, zero-padded tokens >= 49
  const bool vok = (l < TOK);
  const int tsl = ((l >> 3) & 7);
  const int tlo = l & 7;
#pragma unroll
  for (int j = 0; j < 4; j++) {
#pragma unroll
    for (int c = 0; c < 4; c++) {
      uint32_t u = vr[j][c];
      int d0 = j * 8 + c * 2;
      Vt[(d0 + 0) * 64 + ((tsl ^ ((d0 + 0) & 7)) << 3) + tlo] =
          vok ? (unsigned short)(u & 0xFFFFu) : (unsigned short)0;
      Vt[(d0 + 1) * 64 + ((tsl ^ ((d0 + 1) & 7)) << 3) + tlo] =
          vok ? (unsigned short)(u >> 16) : (unsigned short)0;
    }
  }

  // scale + window mask
  const float* mrow = mask + (size_t)(b & 63) * (TOK * TOK);
#pragma unroll
  for (int i = 0; i < 4; i++) {
#pragma unroll
    for (int r = 0; r < 4; r++) {
      int row = i * 16 + lq * 4 + r;
#pragma unroll
      for (int j = 0; j < 4; j++) {
        int col = j * 16 + l15;
        float xv = s[i][j][r] * ATT_SCALE;
        if (col < TOK) {
          if (row < TOK) xv += mrow[row * TOK + col];
        } else {
          xv = -1e30f;
        }
        s[i][j][r] = xv;
      }
    }
  }

  // row softmax; unnormalized P -> LDS bf16 (swizzled)
  float rinv[4][4];
#pragma unroll
  for (int i = 0; i < 4; i++) {
#pragma unroll
    for (int r = 0; r < 4; r++) {
      float m = fmaxf(fmaxf(s[i][0][r], s[i][1][r]), fmaxf(s[i][2][r], s[i][3][r]));
      m = fmaxf(m, __shfl_xor(m, 1));
      m = fmaxf(m, __shfl_xor(m, 2));
      m = fmaxf(m, __shfl_xor(m, 4));
      m = fmaxf(m, __shfl_xor(m, 8));
      float sum = 0.f;
      int row = i * 16 + lq * 4 + r;
#pragma unroll
      for (int j = 0; j < 4; j++) {
        float p = __expf(s[i][j][r] - m);
        sum += p;
        P[row * 64 + (((j * 2 + (l15 >> 3)) ^ (row & 7)) << 3) + (l15 & 7)] =
            f2bf(p);
      }
      sum += __shfl_xor(sum, 1);
      sum += __shfl_xor(sum, 2);
      sum += __shfl_xor(sum, 4);
      sum += __shfl_xor(sum, 8);
      rinv[i][r] = 1.0f / sum;
    }
  }

  asm volatile("s_waitcnt lgkmcnt(0)" ::: "memory");
  __builtin_amdgcn_sched_barrier(0);

  // O = P @ V (K = 64 padded tokens, N = 32 dims)
  f32x4 o[4][2] = {};
#pragma unroll
  for (int ks = 0; ks < 2; ks++) {
    bf16x8 pa[4], vf[2];
#pragma unroll
    for (int i = 0; i < 4; i++)
      pa[i] = __builtin_bit_cast(
          bf16x8,
          *(const u32x4*)&P[(i * 16 + l15) * 64 + (((lq + ks * 4) ^ (l15 & 7)) << 3)]);
#pragma unroll
    for (int j = 0; j < 2; j++)
      vf[j] = __builtin_bit_cast(
          bf16x8,
          *(const u32x4*)&Vt[(j * 16 + l15) * 64 + (((lq + ks * 4) ^ (l15 & 7)) << 3)]);
    __builtin_amdgcn_s_setprio(1);
#pragma unroll
    for (int i = 0; i < 4; i++) {
#pragma unroll
      for (int j = 0; j < 2; j++) o[i][j] = mfma16(pa[i], vf[j], o[i][j]);
    }
    __builtin_amdgcn_s_setprio(0);
  }

#pragma unroll
  for (int i = 0; i < 4; i++) {
#pragma unroll
    for (int r = 0; r < 4; r++) {
      int row = i * 16 + lq * 4 + r;
      if (row < TOK) {
        float inv = rinv[i][r];
        size_t obase = ((size_t)b * TOK + row) * CDIM + h * HDIM;
#pragma unroll
        for (int j = 0; j < 2; j++)
          ao[obase + j * 16 + l15] = f2bf(o[i][j][r] * inv);
      }
    }
  }
}

extern "C" void kernel_launch(void* const* d_in, const int* in_sizes, int n_in,
                              void* d_out, int out_size, void* d_ws,
                              size_t ws_size, hipStream_t stream) {
  const float* x = (const float*)d_in[0];
  const float* mask = (const float*)d_in[1];
  const float* Wqkv = (const float*)d_in[2];
  const float* bqkv = (const float*)d_in[3];
  const float* Adown = (const float*)d_in[4];
  const float* Bup = (const float*)d_in[5];
  const float* Wproj = (const float*)d_in[6];
  const float* bproj = (const float*)d_in[7];
  float* out = (float*)d_out;
  char* ws = (char*)d_ws;

  size_t off = 0;
  auto alloc = [&](size_t bytes) {
    size_t o = off;
    off += (bytes + 255) & ~(size_t)255;
    return o;
  };
  const size_t qkv_elems = (size_t)NB * NHEAD * TOK * HDIM;
  unsigned short* weff = (unsigned short*)(ws + alloc((size_t)3 * CDIM * CDIM * 2));
  unsigned short* wpb = (unsigned short*)(ws + alloc((size_t)CDIM * CDIM * 2));
  unsigned short* qb = (unsigned short*)(ws + alloc(qkv_elems * 2 + 4096));
  unsigned short* kb = (unsigned short*)(ws + alloc(qkv_elems * 2 + 4096));
  unsigned short* vb = (unsigned short*)(ws + alloc(qkv_elems * 2 + 4096));
  unsigned short* ao = (unsigned short*)(ws + alloc((size_t)MTOT * CDIM * 2));

  k_prep_weff<<<(3 * CDIM * CDIM + 255) / 256, 256, 0, stream>>>(Wqkv, Bup,
                                                                 Adown, weff);
  k_conv4<<<256, 256, 0, stream>>>(Wproj, wpb, CDIM * CDIM / 4);
  // QKV (fused x fp32->bf16): 392 m-tiles x 6 n-tiles = 2352 blocks
  k_gemm256<6, true, true><<<(MTOT / 256) * 6, 512, 0, stream>>>(
      x, weff, bqkv, qb, kb, vb, nullptr);
  k_attn<<<NB * NHEAD / 4, 256, 0, stream>>>(qb, kb, vb, mask, ao);
  // proj: 392 x 2 = 784 blocks
  k_gemm256<2, false, false><<<(MTOT / 256) * 2, 512, 0, stream>>>(
      ao, wpb, bproj, nullptr, nullptr, nullptr, out);
}

// Round 7
// 561.424 us; speedup vs baseline: 1.0391x; 1.0391x over previous
//
#include <hip/hip_runtime.h>
#include <stdint.h>

typedef __attribute__((ext_vector_type(4))) float f32x4;
typedef __attribute__((ext_vector_type(8))) __bf16 bf16x8;
typedef __attribute__((ext_vector_type(4))) unsigned int u32x4;
typedef __attribute__((ext_vector_type(4))) unsigned short u16x4;

#define TOK 49
#define NHEAD 16
#define HDIM 32
#define CDIM 512
#define NB 2048
#define MTOT (NB * TOK) /* 100352 */
#define ATT_SCALE 0.17677669529663687f

__device__ __forceinline__ unsigned short f2bf(float f) {
  uint32_t u = __builtin_bit_cast(uint32_t, f);
  u += 0x7FFFu + ((u >> 16) & 1u);
  return (unsigned short)(u >> 16);
}

__device__ __forceinline__ void gl_lds16(const void* g, const void* lds) {
  __builtin_amdgcn_global_load_lds(
      (__attribute__((address_space(1))) void*)(uintptr_t)g,
      (__attribute__((address_space(3))) void*)(uint32_t)(uintptr_t)lds,
      16, 0, 0);
}

__device__ __forceinline__ f32x4 mfma16(bf16x8 a, bf16x8 b, f32x4 c) {
  return __builtin_amdgcn_mfma_f32_16x16x32_bf16(a, b, c, 0, 0, 0);
}

// ---- K0a: W_eff = W_qkv + B_up @ A_down, to bf16 [1536][512] ----
__global__ __launch_bounds__(256) void k_prep_weff(
    const float* __restrict__ Wqkv, const float* __restrict__ Bup,
    const float* __restrict__ Adown, unsigned short* __restrict__ weff) {
  int idx = blockIdx.x * 256 + threadIdx.x;
  if (idx >= 3 * CDIM * CDIM) return;
  int o = idx >> 9, i = idx & 511;
  float v = Wqkv[idx];
#pragma unroll
  for (int r = 0; r < 4; r++) v += Bup[o * 4 + r] * Adown[r * 512 + i];
  weff[idx] = f2bf(v);
}

// ---- K0b: fp32 -> bf16 vectorized convert ----
__global__ __launch_bounds__(256) void k_conv4(
    const float* __restrict__ src, unsigned short* __restrict__ dst, int n4) {
  for (int i = blockIdx.x * blockDim.x + threadIdx.x; i < n4;
       i += gridDim.x * blockDim.x) {
    f32x4 v = *(const f32x4*)(src + (size_t)i * 4);
    u16x4 o;
    o[0] = f2bf(v[0]); o[1] = f2bf(v[1]); o[2] = f2bf(v[2]); o[3] = f2bf(v[3]);
    *(u16x4*)(dst + (size_t)i * 4) = o;
  }
}

// ---- QKV: 256x256 tile, BK=64, 8-wave, counted-vmcnt dbuf (R5 structure) ----
// C = A @ Bw^T + bias, split-scattered to q/k/v. A [M][512] bf16, Bw [1536][512].
// LDS 16B slots XOR-swizzled via pre-swizzled global source; conflict-free
// LDS-staged coalesced epilogue (R6-verified, 0 bank conflicts).
__global__ __launch_bounds__(512, 1) void k_gemm256qkv(
    const unsigned short* __restrict__ A, const unsigned short* __restrict__ Bw,
    const float* __restrict__ bias,
    unsigned short* __restrict__ qo, unsigned short* __restrict__ ko,
    unsigned short* __restrict__ vo) {
  __shared__ __attribute__((aligned(16))) unsigned short smem[65536];
  const int t = threadIdx.x;
  const int l = t & 63;
  const int l15 = l & 15, lq = l >> 4;
  const int w = t >> 6;
  const int wr = w >> 2, wc = w & 3;  // 2 x 4 wave grid, wave owns 128x64
  const int bid = blockIdx.x;
  const int lb = (bid & 7) * ((int)gridDim.x >> 3) + (bid >> 3);
  const int mt = lb / 6, nt = lb % 6;
  const size_t m0 = (size_t)mt * 256;
  const int n0 = nt * 256;

  auto stageA = [&](int kt, int bb) {
    unsigned short* dst = smem + bb * 16384;
#pragma unroll
    for (int q = 0; q < 4; ++q) {
      const int li = q * 512 + t;  // 16B-chunk index in 256x64 tile
      const int row = li >> 3, sl = li & 7;
      gl_lds16(A + (m0 + row) * CDIM + kt * 64 + ((sl ^ (row & 7)) << 3),
               &dst[li * 8]);
    }
  };
  auto stageB = [&](int kt, int bb) {
    unsigned short* dst = smem + 32768 + bb * 16384;
#pragma unroll
    for (int q = 0; q < 4; ++q) {
      const int li = q * 512 + t;
      const int row = li >> 3, sl = li & 7;
      gl_lds16(Bw + (size_t)(n0 + row) * CDIM + kt * 64 + ((sl ^ (row & 7)) << 3),
               &dst[li * 8]);
    }
  };

  f32x4 acc[8][4] = {};
  stageA(0, 0);
  stageB(0, 0);
  for (int kt = 0; kt < 8; ++kt) {
    const int cur = kt & 1, nb = cur ^ 1;
    if (kt < 7) {
      stageA(kt + 1, nb);
      stageB(kt + 1, nb);
      // tile kt's 8 loads landed; tile kt+1's 8 stay in flight (counted)
      asm volatile("s_waitcnt vmcnt(8)" ::: "memory");
    } else {
      asm volatile("s_waitcnt vmcnt(0)" ::: "memory");
    }
    __builtin_amdgcn_s_barrier();
    asm volatile("" ::: "memory");  // keep ds_reads below the barrier
    const unsigned short* bufA = smem + cur * 16384;
    const unsigned short* bufB = smem + 32768 + cur * 16384;

    // B fragments: loaded ONCE per K-tile, live across all 4 phases
    bf16x8 bfr[4][2];
#pragma unroll
    for (int c = 0; c < 4; ++c) {
      const int r = wc * 64 + c * 16 + l15;
#pragma unroll
      for (int h = 0; h < 2; ++h)
        bfr[c][h] = __builtin_bit_cast(
            bf16x8,
            *(const u32x4*)&bufB[r * 64 + (((lq + h * 4) ^ (r & 7)) << 3)]);
    }

#pragma unroll
    for (int p = 0; p < 4; ++p) {
      bf16x8 af[2][2];
#pragma unroll
      for (int rr = 0; rr < 2; ++rr) {
        const int r = wr * 128 + (p * 2 + rr) * 16 + l15;
#pragma unroll
        for (int h = 0; h < 2; ++h)
          af[rr][h] = __builtin_bit_cast(
              bf16x8,
              *(const u32x4*)&bufA[r * 64 + (((lq + h * 4) ^ (r & 7)) << 3)]);
      }
      __builtin_amdgcn_s_setprio(1);
#pragma unroll
      for (int rr = 0; rr < 2; ++rr) {
#pragma unroll
        for (int c = 0; c < 4; ++c) {
          acc[p * 2 + rr][c] = mfma16(af[rr][0], bfr[c][0], acc[p * 2 + rr][c]);
          acc[p * 2 + rr][c] = mfma16(af[rr][1], bfr[c][1], acc[p * 2 + rr][c]);
        }
      }
      __builtin_amdgcn_s_setprio(0);
    }
    asm volatile("" ::: "memory");
    __builtin_amdgcn_s_barrier();  // all reads of buf[cur] done
  }

  // ---- LDS-staged coalesced epilogue (slot^row swizzled; R6: 0 conflicts) ----
  __syncthreads();
  unsigned short* ep = smem + w * 8192;  // 128 rows x 64 cols bf16 (16KB)
#pragma unroll
  for (int J = 0; J < 4; ++J) {
    const int colb = n0 + wc * 64 + J * 16 + l15;
    const float bv = bias[colb];
    const int sl0 = J * 2 + (l15 >> 3);
#pragma unroll
    for (int I = 0; I < 8; ++I) {
#pragma unroll
      for (int r = 0; r < 4; ++r) {
        const int row = I * 16 + lq * 4 + r;
        ep[row * 64 + ((sl0 ^ (row & 7)) << 3) + (l15 & 7)] =
            f2bf(acc[I][J][r] + bv);
      }
    }
  }
  __syncthreads();
#pragma unroll
  for (int rnd = 0; rnd < 16; ++rnd) {
    const int sub = rnd * 16 + (l >> 2);
    const int mloc = sub >> 1, hd2 = sub & 1;
    const int colh = n0 + wc * 64 + hd2 * 32;
    const int which = colh >> 9;
    const int hh = (colh >> 5) & 15;
    unsigned short* dst = which == 0 ? qo : (which == 1 ? ko : vo);
    const uint32_t mg = (uint32_t)(m0 + wr * 128 + mloc);
    const uint32_t bw_ = mg / 49u;
    const uint32_t nn = mg - bw_ * 49u;
    const int sl = hd2 * 4 + (l & 3);
    u32x4 v = *(const u32x4*)&ep[mloc * 64 + ((sl ^ (mloc & 7)) << 3)];
    *(u32x4*)&dst[((size_t)(bw_ * 16u + hh) * 49u + nn) * 32u + (l & 3) * 8] = v;
  }
}

// ---- proj: 128x128 tile, BK=32, 4-wave, ~3 blocks/CU (occupancy lever) ----
// C = A @ Bw^T + bias, fp32 out. A [M][512] bf16, Bw [512][512] bf16.
// 32KB LDS dbuf; counted vmcnt(4); BK=32 swizzle slot^=(row>>1)&3 (2-way=free).
__global__ __launch_bounds__(256, 3) void k_gemm128(
    const unsigned short* __restrict__ A, const unsigned short* __restrict__ Bw,
    const float* __restrict__ bias, float* __restrict__ fo) {
  __shared__ __attribute__((aligned(16))) unsigned short smem[16384];  // 32KB
  const int t = threadIdx.x;  // 256
  const int l = t & 63;
  const int l15 = l & 15, lq = l >> 4;
  const int w = t >> 6;               // 4 waves
  const int wr = w >> 1, wc = w & 1;  // 2x2, wave owns 64x64
  const int bid = blockIdx.x;
  const int lb = (bid & 7) * ((int)gridDim.x >> 3) + (bid >> 3);
  const int mt = lb / 4, nt = lb % 4;
  const size_t m0 = (size_t)mt * 128;
  const int n0 = nt * 128;

  auto stageA = [&](int kt, int bb) {
    unsigned short* dst = smem + bb * 4096;
#pragma unroll
    for (int q = 0; q < 2; ++q) {
      const int li = q * 256 + t;  // 512 chunks: 128 rows x 4 slots of 16B
      const int row = li >> 2, sl = li & 3;
      gl_lds16(A + (m0 + row) * CDIM + kt * 32 + ((sl ^ ((row >> 1) & 3)) << 3),
               &dst[li * 8]);
    }
  };
  auto stageB = [&](int kt, int bb) {
    unsigned short* dst = smem + 8192 + bb * 4096;
#pragma unroll
    for (int q = 0; q < 2; ++q) {
      const int li = q * 256 + t;
      const int row = li >> 2, sl = li & 3;
      gl_lds16(Bw + (size_t)(n0 + row) * CDIM + kt * 32 +
                   ((sl ^ ((row >> 1) & 3)) << 3),
               &dst[li * 8]);
    }
  };

  f32x4 acc[4][4] = {};
  stageA(0, 0);
  stageB(0, 0);
  for (int kt = 0; kt < 16; ++kt) {
    const int cur = kt & 1, nb = cur ^ 1;
    if (kt < 15) {
      stageA(kt + 1, nb);
      stageB(kt + 1, nb);
      asm volatile("s_waitcnt vmcnt(4)" ::: "memory");
    } else {
      asm volatile("s_waitcnt vmcnt(0)" ::: "memory");
    }
    __builtin_amdgcn_s_barrier();
    asm volatile("" ::: "memory");
    const unsigned short* bufA = smem + cur * 4096;
    const unsigned short* bufB = smem + 8192 + cur * 4096;
    bf16x8 af[4], bfv[4];
#pragma unroll
    for (int f = 0; f < 4; ++f) {
      const int r = wr * 64 + f * 16 + l15;
      af[f] = __builtin_bit_cast(
          bf16x8, *(const u32x4*)&bufA[r * 32 + ((lq ^ ((r >> 1) & 3)) << 3)]);
    }
#pragma unroll
    for (int c = 0; c < 4; ++c) {
      const int r = wc * 64 + c * 16 + l15;
      bfv[c] = __builtin_bit_cast(
          bf16x8, *(const u32x4*)&bufB[r * 32 + ((lq ^ ((r >> 1) & 3)) << 3)]);
    }
    __builtin_amdgcn_s_setprio(1);
#pragma unroll
    for (int f = 0; f < 4; ++f) {
#pragma unroll
      for (int c = 0; c < 4; ++c) acc[f][c] = mfma16(af[f], bfv[c], acc[f][c]);
    }
    __builtin_amdgcn_s_setprio(0);
    asm volatile("" ::: "memory");
    __builtin_amdgcn_s_barrier();
  }

  // ---- LDS-staged coalesced fp32 epilogue (per-wave region, no block sync
  // needed after the initial one; swizzled slots) ----
  __syncthreads();
  float* ep32 = (float*)smem + w * 2048;  // 32 rows x 64 cols f32 (8KB)
#pragma unroll
  for (int ch = 0; ch < 2; ++ch) {
#pragma unroll
    for (int J = 0; J < 4; ++J) {
      const int colb = n0 + wc * 64 + J * 16 + l15;
      const float bv = bias[colb];
      const int sl0 = J * 4 + (l15 >> 2);
#pragma unroll
      for (int Ii = 0; Ii < 2; ++Ii) {
#pragma unroll
        for (int r = 0; r < 4; ++r) {
          const int row = Ii * 16 + lq * 4 + r;
          ep32[row * 64 + ((sl0 ^ (row & 7)) << 2) + (l15 & 3)] =
              acc[ch * 2 + Ii][J][r] + bv;
        }
      }
    }
    asm volatile("s_waitcnt lgkmcnt(0)" ::: "memory");
#pragma unroll
    for (int rnd = 0; rnd < 8; ++rnd) {
      const int row = rnd * 4 + (l >> 4);
      const int sl = l & 15;
      f32x4 v = *(const f32x4*)&ep32[row * 64 + ((sl ^ (row & 7)) << 2)];
      const size_t mg = m0 + wr * 64 + ch * 32 + row;
      *(f32x4*)&fo[mg * CDIM + n0 + wc * 64 + (l & 15) * 4] = v;
    }
    asm volatile("s_waitcnt lgkmcnt(0)" ::: "memory");
    asm volatile("" ::: "memory");
  }
}

// ---- K2: window attention, one wave per (b,h) ---- (unchanged)
__global__ __launch_bounds__(256) void k_attn(
    const unsigned short* __restrict__ qb, const unsigned short* __restrict__ kb,
    const unsigned short* __restrict__ vb, const float* __restrict__ mask,
    unsigned short* __restrict__ ao) {
  __shared__ __attribute__((aligned(16))) unsigned short sP[4][64 * 64];
  __shared__ __attribute__((aligned(16))) unsigned short sV[4][32 * 64];
  const int t = threadIdx.x;
  const int l = t & 63, w = t >> 6;
  const int l15 = l & 15, lq = l >> 4;
  const int pair = blockIdx.x * 4 + w;
  const int b = pair >> 4, h = pair & 15;
  const size_t base = (size_t)pair * (TOK * HDIM);
  unsigned short* P = sP[w];
  unsigned short* Vt = sV[w];

  bf16x8 qf[4], kf[4];
#pragma unroll
  for (int i = 0; i < 4; i++)
    qf[i] = __builtin_bit_cast(
        bf16x8, *(const u32x4*)(qb + base + (size_t)(i * 16 + l15) * 32 + lq * 8));
#pragma unroll
  for (int i = 0; i < 4; i++)
    kf[i] = __builtin_bit_cast(
        bf16x8, *(const u32x4*)(kb + base + (size_t)(i * 16 + l15) * 32 + lq * 8));
  u32x4 vr[4];
#pragma unroll
  for (int j = 0; j < 4; j++)
    vr[j] = *(const u32x4*)(vb + base + (size_t)l * 32 + j * 8);

  f32x4 s[4][4];
  __builtin_amdgcn_s_setprio(1);
#pragma unroll
  for (int i = 0; i < 4; i++) {
#pragma unroll
    for (int j = 0; j < 4; j++) s[i][j] = mfma16(qf[i], kf[j], (f32x4)0.0f);
  }
  __builtin_amdgcn_s_setprio(0);

  const bool vok = (l < TOK);
  const int tsl = ((l >> 3) & 7);
  const int tlo = l & 7;
#pragma unroll
  for (int j = 0; j < 4; j++) {
#pragma unroll
    for (int c = 0; c < 4; c++) {
      uint32_t u = vr[j][c];
      int d0 = j * 8 + c * 2;
      Vt[(d0 + 0) * 64 + ((tsl ^ ((d0 + 0) & 7)) << 3) + tlo] =
          vok ? (unsigned short)(u & 0xFFFFu) : (unsigned short)0;
      Vt[(d0 + 1) * 64 + ((tsl ^ ((d0 + 1) & 7)) << 3) + tlo] =
          vok ? (unsigned short)(u >> 16) : (unsigned short)0;
    }
  }

  const float* mrow = mask + (size_t)(b & 63) * (TOK * TOK);
#pragma unroll
  for (int i = 0; i < 4; i++) {
#pragma unroll
    for (int r = 0; r < 4; r++) {
      int row = i * 16 + lq * 4 + r;
#pragma unroll
      for (int j = 0; j < 4; j++) {
        int col = j * 16 + l15;
        float xv = s[i][j][r] * ATT_SCALE;
        if (col < TOK) {
          if (row < TOK) xv += mrow[row * TOK + col];
        } else {
          xv = -1e30f;
        }
        s[i][j][r] = xv;
      }
    }
  }

  float rinv[4][4];
#pragma unroll
  for (int i = 0; i < 4; i++) {
#pragma unroll
    for (int r = 0; r < 4; r++) {
      float m = fmaxf(fmaxf(s[i][0][r], s[i][1][r]), fmaxf(s[i][2][r], s[i][3][r]));
      m = fmaxf(m, __shfl_xor(m, 1));
      m = fmaxf(m, __shfl_xor(m, 2));
      m = fmaxf(m, __shfl_xor(m, 4));
      m = fmaxf(m, __shfl_xor(m, 8));
      float sum = 0.f;
      int row = i * 16 + lq * 4 + r;
#pragma unroll
      for (int j = 0; j < 4; j++) {
        float p = __expf(s[i][j][r] - m);
        sum += p;
        P[row * 64 + (((j * 2 + (l15 >> 3)) ^ (row & 7)) << 3) + (l15 & 7)] =
            f2bf(p);
      }
      sum += __shfl_xor(sum, 1);
      sum += __shfl_xor(sum, 2);
      sum += __shfl_xor(sum, 4);
      sum += __shfl_xor(sum, 8);
      rinv[i][r] = 1.0f / sum;
    }
  }

  asm volatile("s_waitcnt lgkmcnt(0)" ::: "memory");
  __builtin_amdgcn_sched_barrier(0);

  f32x4 o[4][2] = {};
#pragma unroll
  for (int ks = 0; ks < 2; ks++) {
    bf16x8 pa[4], vf[2];
#pragma unroll
    for (int i = 0; i < 4; i++)
      pa[i] = __builtin_bit_cast(
          bf16x8,
          *(const u32x4*)&P[(i * 16 + l15) * 64 + (((lq + ks * 4) ^ (l15 & 7)) << 3)]);
#pragma unroll
    for (int j = 0; j < 2; j++)
      vf[j] = __builtin_bit_cast(
          bf16x8,
          *(const u32x4*)&Vt[(j * 16 + l15) * 64 + (((lq + ks * 4) ^ (l15 & 7)) << 3)]);
    __builtin_amdgcn_s_setprio(1);
#pragma unroll
    for (int i = 0; i < 4; i++) {
#pragma unroll
      for (int j = 0; j < 2; j++) o[i][j] = mfma16(pa[i], vf[j], o[i][j]);
    }
    __builtin_amdgcn_s_setprio(0);
  }

#pragma unroll
  for (int i = 0; i < 4; i++) {
#pragma unroll
    for (int r = 0; r < 4; r++) {
      int row = i * 16 + lq * 4 + r;
      if (row < TOK) {
        float inv = rinv[i][r];
        size_t obase = ((size_t)b * TOK + row) * CDIM + h * HDIM;
#pragma unroll
        for (int j = 0; j < 2; j++)
          ao[obase + j * 16 + l15] = f2bf(o[i][j][r] * inv);
      }
    }
  }
}

extern "C" void kernel_launch(void* const* d_in, const int* in_sizes, int n_in,
                              void* d_out, int out_size, void* d_ws,
                              size_t ws_size, hipStream_t stream) {
  const float* x = (const float*)d_in[0];
  const float* mask = (const float*)d_in[1];
  const float* Wqkv = (const float*)d_in[2];
  const float* bqkv = (const float*)d_in[3];
  const float* Adown = (const float*)d_in[4];
  const float* Bup = (const float*)d_in[5];
  const float* Wproj = (const float*)d_in[6];
  const float* bproj = (const float*)d_in[7];
  float* out = (float*)d_out;
  char* ws = (char*)d_ws;

  size_t off = 0;
  auto alloc = [&](size_t bytes) {
    size_t o = off;
    off += (bytes + 255) & ~(size_t)255;
    return o;
  };
  const size_t qkv_elems = (size_t)NB * NHEAD * TOK * HDIM;
  unsigned short* weff = (unsigned short*)(ws + alloc((size_t)3 * CDIM * CDIM * 2));
  unsigned short* wpb = (unsigned short*)(ws + alloc((size_t)CDIM * CDIM * 2));
  unsigned short* qb = (unsigned short*)(ws + alloc(qkv_elems * 2 + 4096));
  unsigned short* kb = (unsigned short*)(ws + alloc(qkv_elems * 2 + 4096));
  unsigned short* vb = (unsigned short*)(ws + alloc(qkv_elems * 2 + 4096));
  unsigned short* xb = (unsigned short*)(ws + alloc((size_t)MTOT * CDIM * 2));
  unsigned short* ao = xb;  // xb dead after QKV GEMM; reuse for attention out

  k_prep_weff<<<(3 * CDIM * CDIM + 255) / 256, 256, 0, stream>>>(Wqkv, Bup,
                                                                 Adown, weff);
  k_conv4<<<256, 256, 0, stream>>>(Wproj, wpb, CDIM * CDIM / 4);
  k_conv4<<<2048, 256, 0, stream>>>(x, xb, MTOT * CDIM / 4);
  // QKV: 392 m-tiles x 6 n-tiles = 2352 blocks (2352 % 8 == 0)
  k_gemm256qkv<<<(MTOT / 256) * 6, 512, 0, stream>>>(xb, weff, bqkv, qb, kb, vb);
  k_attn<<<NB * NHEAD / 4, 256, 0, stream>>>(qb, kb, vb, mask, ao);
  // proj: 784 m-tiles x 4 n-tiles = 3136 blocks (3136 % 8 == 0)
  k_gemm128<<<(MTOT / 128) * 4, 256, 0, stream>>>(ao, wpb, bproj, out);
}

// Round 8
// 559.306 us; speedup vs baseline: 1.0430x; 1.0038x over previous
//
#include <hip/hip_runtime.h>
#include <stdint.h>

typedef __attribute__((ext_vector_type(4))) float f32x4;
typedef __attribute__((ext_vector_type(8))) __bf16 bf16x8;
typedef __attribute__((ext_vector_type(4))) unsigned int u32x4;
typedef __attribute__((ext_vector_type(4))) unsigned short u16x4;

#define TOK 49
#define NHEAD 16
#define HDIM 32
#define CDIM 512
#define NB 2048
#define MTOT (NB * TOK) /* 100352 */
#define ATT_SCALE 0.17677669529663687f

__device__ __forceinline__ unsigned short f2bf(float f) {
  uint32_t u = __builtin_bit_cast(uint32_t, f);
  u += 0x7FFFu + ((u >> 16) & 1u);
  return (unsigned short)(u >> 16);
}

__device__ __forceinline__ void gl_lds16(const void* g, const void* lds) {
  __builtin_amdgcn_global_load_lds(
      (__attribute__((address_space(1))) void*)(uintptr_t)g,
      (__attribute__((address_space(3))) void*)(uint32_t)(uintptr_t)lds,
      16, 0, 0);
}

__device__ __forceinline__ f32x4 mfma16(bf16x8 a, bf16x8 b, f32x4 c) {
  return __builtin_amdgcn_mfma_f32_16x16x32_bf16(a, b, c, 0, 0, 0);
}

// ---- K0a: W_eff = W_qkv + B_up @ A_down, to bf16 [1536][512] ----
__global__ __launch_bounds__(256) void k_prep_weff(
    const float* __restrict__ Wqkv, const float* __restrict__ Bup,
    const float* __restrict__ Adown, unsigned short* __restrict__ weff) {
  int idx = blockIdx.x * 256 + threadIdx.x;
  if (idx >= 3 * CDIM * CDIM) return;
  int o = idx >> 9, i = idx & 511;
  float v = Wqkv[idx];
#pragma unroll
  for (int r = 0; r < 4; r++) v += Bup[o * 4 + r] * Adown[r * 512 + i];
  weff[idx] = f2bf(v);
}

// ---- K0b: fp32 -> bf16 vectorized convert ----
__global__ __launch_bounds__(256) void k_conv4(
    const float* __restrict__ src, unsigned short* __restrict__ dst, int n4) {
  for (int i = blockIdx.x * blockDim.x + threadIdx.x; i < n4;
       i += gridDim.x * blockDim.x) {
    f32x4 v = *(const f32x4*)(src + (size_t)i * 4);
    u16x4 o;
    o[0] = f2bf(v[0]); o[1] = f2bf(v[1]); o[2] = f2bf(v[2]); o[3] = f2bf(v[3]);
    *(u16x4*)(dst + (size_t)i * 4) = o;
  }
}

// ---- QKV: 256x256 tile, BK=32, TRIPLE-buffered, 1 barrier/tile ----
// Hazard ledger: stage(kt+2) -> buf[(kt+2)%3], whose reads (tile kt-1) ended
// before tile kt's top barrier => no WAR. Reads of tile kt hit data staged 2
// tiles (~1000+cyc) earlier; gate = counted vmcnt(4) (kt+1's loads fly on).
// No mid-tile barriers; compiler handles ds_read->MFMA lgkmcnt.
__global__ __launch_bounds__(512, 1) void k_gemm256qkv(
    const unsigned short* __restrict__ A, const unsigned short* __restrict__ Bw,
    const float* __restrict__ bias,
    unsigned short* __restrict__ qo, unsigned short* __restrict__ ko,
    unsigned short* __restrict__ vo) {
  // 96KB tiles + epilogue reuse: A bufs [3][8192], B bufs [3][8192] ushorts.
  __shared__ __attribute__((aligned(16))) unsigned short smem[49152];
  const int t = threadIdx.x;
  const int l = t & 63;
  const int l15 = l & 15, lq = l >> 4;
  const int w = t >> 6;
  const int wr = w >> 2, wc = w & 3;  // 2 x 4 wave grid, wave owns 128x64
  const int bid = blockIdx.x;
  const int lb = (bid & 7) * ((int)gridDim.x >> 3) + (bid >> 3);
  const int mt = lb / 6, nt = lb % 6;
  const size_t m0 = (size_t)mt * 256;
  const int n0 = nt * 256;

  // A tile 256x32 bf16 = 16KB = 1024 chunks of 16B; 2 chunks/thread.
  auto stage = [&](int kt, int bb) {
    unsigned short* dA = smem + bb * 8192;
    unsigned short* dB = smem + 24576 + bb * 8192;
#pragma unroll
    for (int q = 0; q < 2; ++q) {
      const int li = q * 512 + t;
      const int row = li >> 2, sl = li & 3;
      const int kof = kt * 32 + ((sl ^ ((row >> 1) & 3)) << 3);
      gl_lds16(A + (m0 + row) * CDIM + kof, &dA[li * 8]);
    }
#pragma unroll
    for (int q = 0; q < 2; ++q) {
      const int li = q * 512 + t;
      const int row = li >> 2, sl = li & 3;
      const int kof = kt * 32 + ((sl ^ ((row >> 1) & 3)) << 3);
      gl_lds16(Bw + (size_t)(n0 + row) * CDIM + kof, &dB[li * 8]);
    }
  };

  f32x4 acc[8][4] = {};
  stage(0, 0);
  stage(1, 1);
  for (int kt = 0; kt < 16; ++kt) {
    const int cur = kt % 3;
    if (kt < 15) {
      asm volatile("s_waitcnt vmcnt(4)" ::: "memory");  // tile kt landed
    } else {
      asm volatile("s_waitcnt vmcnt(0)" ::: "memory");
    }
    __builtin_amdgcn_s_barrier();
    asm volatile("" ::: "memory");
    if (kt < 14) stage(kt + 2, (kt + 2) % 3);  // -> buffer freed at kt-1
    const unsigned short* bufA = smem + cur * 8192;
    const unsigned short* bufB = smem + 24576 + cur * 8192;
    bf16x8 bfv[4], af[8];
#pragma unroll
    for (int c = 0; c < 4; ++c) {
      const int r = wc * 64 + c * 16 + l15;
      bfv[c] = __builtin_bit_cast(
          bf16x8, *(const u32x4*)&bufB[r * 32 + ((lq ^ ((r >> 1) & 3)) << 3)]);
    }
#pragma unroll
    for (int f = 0; f < 8; ++f) {
      const int r = wr * 128 + f * 16 + l15;
      af[f] = __builtin_bit_cast(
          bf16x8, *(const u32x4*)&bufA[r * 32 + ((lq ^ ((r >> 1) & 3)) << 3)]);
    }
    __builtin_amdgcn_s_setprio(1);
#pragma unroll
    for (int f = 0; f < 8; ++f) {
#pragma unroll
      for (int c = 0; c < 4; ++c) acc[f][c] = mfma16(af[f], bfv[c], acc[f][c]);
    }
    __builtin_amdgcn_s_setprio(0);
    asm volatile("" ::: "memory");
  }

  // ---- LDS-staged coalesced epilogue (slot^row swizzled; 0 conflicts) ----
  __syncthreads();
  unsigned short* ep = smem + w * 4096;  // 64 rows x 64 cols bf16 (8KB), x2
#pragma unroll
  for (int half = 0; half < 2; ++half) {
#pragma unroll
    for (int J = 0; J < 4; ++J) {
      const int colb = n0 + wc * 64 + J * 16 + l15;
      const float bv = bias[colb];
      const int sl0 = J * 2 + (l15 >> 3);
#pragma unroll
      for (int I = 0; I < 4; ++I) {
#pragma unroll
        for (int r = 0; r < 4; ++r) {
          const int row = I * 16 + lq * 4 + r;
          ep[row * 64 + ((sl0 ^ (row & 7)) << 3) + (l15 & 7)] =
              f2bf(acc[half * 4 + I][J][r] + bv);
        }
      }
    }
    __syncthreads();
    // 128 sub-rows (64 m x 2 heads) of 64B; 8 lanes... 4 lanes per sub-row
#pragma unroll
    for (int rnd = 0; rnd < 8; ++rnd) {
      const int sub = rnd * 16 + (l >> 2);
      const int mloc = sub >> 1, hd2 = sub & 1;
      const int colh = n0 + wc * 64 + hd2 * 32;
      const int which = colh >> 9;
      const int hh = (colh >> 5) & 15;
      unsigned short* dst = which == 0 ? qo : (which == 1 ? ko : vo);
      const uint32_t mg = (uint32_t)(m0 + wr * 128 + half * 64 + mloc);
      const uint32_t bw_ = mg / 49u;
      const uint32_t nn = mg - bw_ * 49u;
      const int sl = hd2 * 4 + (l & 3);
      u32x4 v = *(const u32x4*)&ep[mloc * 64 + ((sl ^ (mloc & 7)) << 3)];
      *(u32x4*)&dst[((size_t)(bw_ * 16u + hh) * 49u + nn) * 32u + (l & 3) * 8] =
          v;
    }
    __syncthreads();
  }
}

// ---- proj: 128x128 tile, BK=32, TRIPLE-buffered, 3 blocks/CU ----
__global__ __launch_bounds__(256, 3) void k_gemm128(
    const unsigned short* __restrict__ A, const unsigned short* __restrict__ Bw,
    const float* __restrict__ bias, float* __restrict__ fo) {
  __shared__ __attribute__((aligned(16))) unsigned short smem[24576];  // 48KB
  const int t = threadIdx.x;  // 256
  const int l = t & 63;
  const int l15 = l & 15, lq = l >> 4;
  const int w = t >> 6;               // 4 waves
  const int wr = w >> 1, wc = w & 1;  // 2x2, wave owns 64x64
  const int bid = blockIdx.x;
  const int lb = (bid & 7) * ((int)gridDim.x >> 3) + (bid >> 3);
  const int mt = lb / 4, nt = lb % 4;
  const size_t m0 = (size_t)mt * 128;
  const int n0 = nt * 128;

  // A tile 128x32 = 8KB = 512 chunks; 2 chunks/thread.
  auto stage = [&](int kt, int bb) {
    unsigned short* dA = smem + bb * 4096;
    unsigned short* dB = smem + 12288 + bb * 4096;
#pragma unroll
    for (int q = 0; q < 2; ++q) {
      const int li = q * 256 + t;
      const int row = li >> 2, sl = li & 3;
      const int kof = kt * 32 + ((sl ^ ((row >> 1) & 3)) << 3);
      gl_lds16(A + (m0 + row) * CDIM + kof, &dA[li * 8]);
    }
#pragma unroll
    for (int q = 0; q < 2; ++q) {
      const int li = q * 256 + t;
      const int row = li >> 2, sl = li & 3;
      const int kof = kt * 32 + ((sl ^ ((row >> 1) & 3)) << 3);
      gl_lds16(Bw + (size_t)(n0 + row) * CDIM + kof, &dB[li * 8]);
    }
  };

  f32x4 acc[4][4] = {};
  stage(0, 0);
  stage(1, 1);
  for (int kt = 0; kt < 16; ++kt) {
    const int cur = kt % 3;
    if (kt < 15) {
      asm volatile("s_waitcnt vmcnt(4)" ::: "memory");
    } else {
      asm volatile("s_waitcnt vmcnt(0)" ::: "memory");
    }
    __builtin_amdgcn_s_barrier();
    asm volatile("" ::: "memory");
    if (kt < 14) stage(kt + 2, (kt + 2) % 3);
    const unsigned short* bufA = smem + cur * 4096;
    const unsigned short* bufB = smem + 12288 + cur * 4096;
    bf16x8 af[4], bfv[4];
#pragma unroll
    for (int c = 0; c < 4; ++c) {
      const int r = wc * 64 + c * 16 + l15;
      bfv[c] = __builtin_bit_cast(
          bf16x8, *(const u32x4*)&bufB[r * 32 + ((lq ^ ((r >> 1) & 3)) << 3)]);
    }
#pragma unroll
    for (int f = 0; f < 4; ++f) {
      const int r = wr * 64 + f * 16 + l15;
      af[f] = __builtin_bit_cast(
          bf16x8, *(const u32x4*)&bufA[r * 32 + ((lq ^ ((r >> 1) & 3)) << 3)]);
    }
    __builtin_amdgcn_s_setprio(1);
#pragma unroll
    for (int f = 0; f < 4; ++f) {
#pragma unroll
      for (int c = 0; c < 4; ++c) acc[f][c] = mfma16(af[f], bfv[c], acc[f][c]);
    }
    __builtin_amdgcn_s_setprio(0);
    asm volatile("" ::: "memory");
  }

  // ---- LDS-staged coalesced fp32 epilogue (per-wave region, swizzled) ----
  __syncthreads();
  float* ep32 = (float*)smem + w * 2048;  // 32 rows x 64 cols f32 (8KB)
#pragma unroll
  for (int ch = 0; ch < 2; ++ch) {
#pragma unroll
    for (int J = 0; J < 4; ++J) {
      const int colb = n0 + wc * 64 + J * 16 + l15;
      const float bv = bias[colb];
      const int sl0 = J * 4 + (l15 >> 2);
#pragma unroll
      for (int Ii = 0; Ii < 2; ++Ii) {
#pragma unroll
        for (int r = 0; r < 4; ++r) {
          const int row = Ii * 16 + lq * 4 + r;
          ep32[row * 64 + ((sl0 ^ (row & 7)) << 2) + (l15 & 3)] =
              acc[ch * 2 + Ii][J][r] + bv;
        }
      }
    }
    asm volatile("s_waitcnt lgkmcnt(0)" ::: "memory");
#pragma unroll
    for (int rnd = 0; rnd < 8; ++rnd) {
      const int row = rnd * 4 + (l >> 4);
      const int sl = l & 15;
      f32x4 v = *(const f32x4*)&ep32[row * 64 + ((sl ^ (row & 7)) << 2)];
      const size_t mg = m0 + wr * 64 + ch * 32 + row;
      *(f32x4*)&fo[mg * CDIM + n0 + wc * 64 + (l & 15) * 4] = v;
    }
    asm volatile("s_waitcnt lgkmcnt(0)" ::: "memory");
    asm volatile("" ::: "memory");
  }
}

// ---- K2: window attention, one wave per (b,h) ---- (unchanged)
__global__ __launch_bounds__(256) void k_attn(
    const unsigned short* __restrict__ qb, const unsigned short* __restrict__ kb,
    const unsigned short* __restrict__ vb, const float* __restrict__ mask,
    unsigned short* __restrict__ ao) {
  __shared__ __attribute__((aligned(16))) unsigned short sP[4][64 * 64];
  __shared__ __attribute__((aligned(16))) unsigned short sV[4][32 * 64];
  const int t = threadIdx.x;
  const int l = t & 63, w = t >> 6;
  const int l15 = l & 15, lq = l >> 4;
  const int pair = blockIdx.x * 4 + w;
  const int b = pair >> 4, h = pair & 15;
  const size_t base = (size_t)pair * (TOK * HDIM);
  unsigned short* P = sP[w];
  unsigned short* Vt = sV[w];

  bf16x8 qf[4], kf[4];
#pragma unroll
  for (int i = 0; i < 4; i++)
    qf[i] = __builtin_bit_cast(
        bf16x8, *(const u32x4*)(qb + base + (size_t)(i * 16 + l15) * 32 + lq * 8));
#pragma unroll
  for (int i = 0; i < 4; i++)
    kf[i] = __builtin_bit_cast(
        bf16x8, *(const u32x4*)(kb + base + (size_t)(i * 16 + l15) * 32 + lq * 8));
  u32x4 vr[4];
#pragma unroll
  for (int j = 0; j < 4; j++)
    vr[j] = *(const u32x4*)(vb + base + (size_t)l * 32 + j * 8);

  f32x4 s[4][4];
  __builtin_amdgcn_s_setprio(1);
#pragma unroll
  for (int i = 0; i < 4; i++) {
#pragma unroll
    for (int j = 0; j < 4; j++) s[i][j] = mfma16(qf[i], kf[j], (f32x4)0.0f);
  }
  __builtin_amdgcn_s_setprio(0);

  const bool vok = (l < TOK);
  const int tsl = ((l >> 3) & 7);
  const int tlo = l & 7;
#pragma unroll
  for (int j = 0; j < 4; j++) {
#pragma unroll
    for (int c = 0; c < 4; c++) {
      uint32_t u = vr[j][c];
      int d0 = j * 8 + c * 2;
      Vt[(d0 + 0) * 64 + ((tsl ^ ((d0 + 0) & 7)) << 3) + tlo] =
          vok ? (unsigned short)(u & 0xFFFFu) : (unsigned short)0;
      Vt[(d0 + 1) * 64 + ((tsl ^ ((d0 + 1) & 7)) << 3) + tlo] =
          vok ? (unsigned short)(u >> 16) : (unsigned short)0;
    }
  }

  const float* mrow = mask + (size_t)(b & 63) * (TOK * TOK);
#pragma unroll
  for (int i = 0; i < 4; i++) {
#pragma unroll
    for (int r = 0; r < 4; r++) {
      int row = i * 16 + lq * 4 + r;
#pragma unroll
      for (int j = 0; j < 4; j++) {
        int col = j * 16 + l15;
        float xv = s[i][j][r] * ATT_SCALE;
        if (col < TOK) {
          if (row < TOK) xv += mrow[row * TOK + col];
        } else {
          xv = -1e30f;
        }
        s[i][j][r] = xv;
      }
    }
  }

  float rinv[4][4];
#pragma unroll
  for (int i = 0; i < 4; i++) {
#pragma unroll
    for (int r = 0; r < 4; r++) {
      float m = fmaxf(fmaxf(s[i][0][r], s[i][1][r]), fmaxf(s[i][2][r], s[i][3][r]));
      m = fmaxf(m, __shfl_xor(m, 1));
      m = fmaxf(m, __shfl_xor(m, 2));
      m = fmaxf(m, __shfl_xor(m, 4));
      m = fmaxf(m, __shfl_xor(m, 8));
      float sum = 0.f;
      int row = i * 16 + lq * 4 + r;
#pragma unroll
      for (int j = 0; j < 4; j++) {
        float p = __expf(s[i][j][r] - m);
        sum += p;
        P[row * 64 + (((j * 2 + (l15 >> 3)) ^ (row & 7)) << 3) + (l15 & 7)] =
            f2bf(p);
      }
      sum += __shfl_xor(sum, 1);
      sum += __shfl_xor(sum, 2);
      sum += __shfl_xor(sum, 4);
      sum += __shfl_xor(sum, 8);
      rinv[i][r] = 1.0f / sum;
    }
  }

  asm volatile("s_waitcnt lgkmcnt(0)" ::: "memory");
  __builtin_amdgcn_sched_barrier(0);

  f32x4 o[4][2] = {};
#pragma unroll
  for (int ks = 0; ks < 2; ks++) {
    bf16x8 pa[4], vf[2];
#pragma unroll
    for (int i = 0; i < 4; i++)
      pa[i] = __builtin_bit_cast(
          bf16x8,
          *(const u32x4*)&P[(i * 16 + l15) * 64 + (((lq + ks * 4) ^ (l15 & 7)) << 3)]);
#pragma unroll
    for (int j = 0; j < 2; j++)
      vf[j] = __builtin_bit_cast(
          bf16x8,
          *(const u32x4*)&Vt[(j * 16 + l15) * 64 + (((lq + ks * 4) ^ (l15 & 7)) << 3)]);
    __builtin_amdgcn_s_setprio(1);
#pragma unroll
    for (int i = 0; i < 4; i++) {
#pragma unroll
      for (int j = 0; j < 2; j++) o[i][j] = mfma16(pa[i], vf[j], o[i][j]);
    }
    __builtin_amdgcn_s_setprio(0);
  }

#pragma unroll
  for (int i = 0; i < 4; i++) {
#pragma unroll
    for (int r = 0; r < 4; r++) {
      int row = i * 16 + lq * 4 + r;
      if (row < TOK) {
        float inv = rinv[i][r];
        size_t obase = ((size_t)b * TOK + row) * CDIM + h * HDIM;
#pragma unroll
        for (int j = 0; j < 2; j++)
          ao[obase + j * 16 + l15] = f2bf(o[i][j][r] * inv);
      }
    }
  }
}

extern "C" void kernel_launch(void* const* d_in, const int* in_sizes, int n_in,
                              void* d_out, int out_size, void* d_ws,
                              size_t ws_size, hipStream_t stream) {
  const float* x = (const float*)d_in[0];
  const float* mask = (const float*)d_in[1];
  const float* Wqkv = (const float*)d_in[2];
  const float* bqkv = (const float*)d_in[3];
  const float* Adown = (const float*)d_in[4];
  const float* Bup = (const float*)d_in[5];
  const float* Wproj = (const float*)d_in[6];
  const float* bproj = (const float*)d_in[7];
  float* out = (float*)d_out;
  char* ws = (char*)d_ws;

  size_t off = 0;
  auto alloc = [&](size_t bytes) {
    size_t o = off;
    off += (bytes + 255) & ~(size_t)255;
    return o;
  };
  const size_t qkv_elems = (size_t)NB * NHEAD * TOK * HDIM;
  unsigned short* weff = (unsigned short*)(ws + alloc((size_t)3 * CDIM * CDIM * 2));
  unsigned short* wpb = (unsigned short*)(ws + alloc((size_t)CDIM * CDIM * 2));
  unsigned short* qb = (unsigned short*)(ws + alloc(qkv_elems * 2 + 4096));
  unsigned short* kb = (unsigned short*)(ws + alloc(qkv_elems * 2 + 4096));
  unsigned short* vb = (unsigned short*)(ws + alloc(qkv_elems * 2 + 4096));
  unsigned short* xb = (unsigned short*)(ws + alloc((size_t)MTOT * CDIM * 2));
  unsigned short* ao = xb;  // xb dead after QKV GEMM; reuse for attention out

  k_prep_weff<<<(3 * CDIM * CDIM + 255) / 256, 256, 0, stream>>>(Wqkv, Bup,
                                                                 Adown, weff);
  k_conv4<<<256, 256, 0, stream>>>(Wproj, wpb, CDIM * CDIM / 4);
  k_conv4<<<2048, 256, 0, stream>>>(x, xb, MTOT * CDIM / 4);
  // QKV: 392 m-tiles x 6 n-tiles = 2352 blocks (2352 % 8 == 0)
  k_gemm256qkv<<<(MTOT / 256) * 6, 512, 0, stream>>>(xb, weff, bqkv, qb, kb, vb);
  k_attn<<<NB * NHEAD / 4, 256, 0, stream>>>(qb, kb, vb, mask, ao);
  // proj: 784 m-tiles x 4 n-tiles = 3136 blocks (3136 % 8 == 0)
  k_gemm128<<<(MTOT / 128) * 4, 256, 0, stream>>>(ao, wpb, bproj, out);
}